// Round 1
// baseline (113.787 us; speedup 1.0000x reference)
//
#include <hip/hip_runtime.h>

// Depthwise cross-correlation: z (64,256,7,7) over x (64,256,31,31) VALID
// -> out (64,256,25,25), scaled 0.001. fp32 end-to-end.
//
// Round 8: wave-autonomous pipeline, ZERO barriers.
//   Theory: R7's block-wide stage -> vmcnt(0)+barrier -> compute -> copy chain
//   convoys across the ~1.8 occupancy rounds (HBM idle during compute, VALU
//   idle during drain): T ~ T_mem + T_valu + T_copy ~ 37us vs 17.6us BW floor.
//   Now each WAVE owns 2 slices: stages its own x (8 gl_lds chunks, slice 0
//   = chunks 0-3), waits vmcnt(4) and computes slice 0 WHILE slice 1 streams,
//   then vmcnt(0) once; slice-0 output stores drain under slice-1 compute.
//   z comes from wave-uniform global loads (no LDS staging) -> LDS 16KB/block
//   -> 10 blocks/CU = 20 waves/CU (was 14). Lanes map (row, col-half):
//   50/64 active per compute phase, acc[13]/lane.
//   Out is staged into the already-consumed x LDS region (wave-local; same-
//   wave DS ops execute in order, so no barrier needed) then copied flat.

#define KH 7
#define KW 7
#define XH 31
#define XW 31
#define OH 25
#define OW 25
#define NSLICE (64 * 256)
#define THREADS 128
#define SPW 2                        // slices per wave
#define SPB (SPW * 2)                // 4 slices per block (2 waves)
#define XSW_DW 2048                  // per-wave LDS buffer (dwords): pre+2*961 <= 1925
#define SLICE_X (XH * XW)            // 961
#define SLICE_O (OH * OW)            // 625
#define X_TOTAL_DW (NSLICE * SLICE_X)

__device__ __forceinline__ void gl_lds16(const float* g, float* l) {
    __builtin_amdgcn_global_load_lds(
        (const __attribute__((address_space(1))) void*)g,
        (__attribute__((address_space(3))) void*)l, 16, 0, 0);
}

__global__ __launch_bounds__(THREADS, 4)
void xcorr_dw_kernel(const float* __restrict__ z,
                     const float* __restrict__ x,
                     float* __restrict__ out) {
    __shared__ float xs[2][XSW_DW];              // per-wave x buffer; reused as out stage
    const int tid  = threadIdx.x;
    const int lane = tid & 63;
    const int wv   = __builtin_amdgcn_readfirstlane(tid >> 6);
    float* __restrict__ xsw = xs[wv];

    const int wslice = blockIdx.x * SPB + wv * SPW;   // 16384/4 = 4096 blocks: no tail
    const int g0r = wslice * SLICE_X;
    const int pre = g0r & 3;                          // 16B-align slack in [0,3]
    const int g0  = g0r - pre;

    // ---- stage 2 slices of x: 8 chunks x (64 lanes x 16B) = 2048 dwords.
    // Chunks 0-3 cover dw [0,1024) >= [pre, pre+961) = slice 0 (+z-free).
    #pragma unroll
    for (int k = 0; k < 8; ++k) {
        const int dw  = k * 256 + lane * 4;
        const int gdw = min(g0 + dw, X_TOTAL_DW - 4);   // clamp: last wave only
        gl_lds16(x + gdw, xsw + dw);
    }

    // wave-uniform z pointer (scalar/broadcast loads; no LDS staging)
    const float* __restrict__ zw = z + (size_t)wslice * (KH * KW);
    float* __restrict__ og = out + (size_t)wslice * SLICE_O;

    // lane -> (col-half h, row oy); 50/64 lanes active in compute phases
    const int h   = (lane >= OH) ? 1 : 0;
    const int oy  = h ? (lane - OH) : lane;
    const bool act = (lane < 2 * OH);
    const int c0  = h ? 13 : 0;     // h=0: cols 0..12 (13), h=1: cols 13..24 (12)

    // ================= phase A: slice 0 (needs chunks 0-3 only) =================
    asm volatile("s_waitcnt vmcnt(4)" ::: "memory");   // first 4 of 8 loads done
    __builtin_amdgcn_sched_barrier(0);
    if (act) {
        float acc[13] = {};
        const float* __restrict__ xrow = xsw + pre;
        #pragma unroll
        for (int i = 0; i < KH; ++i) {
            const float* __restrict__ p = xrow + (oy + i) * XW + c0;
            float f[19];                                  // h=1 reads 1 dw of next row: in-bounds, unused result
            #pragma unroll
            for (int c = 0; c < 19; ++c) f[c] = p[c];
            #pragma unroll
            for (int j = 0; j < KW; ++j) {
                const float w = zw[i * KW + j];           // uniform
                #pragma unroll
                for (int c = 0; c < 13; ++c)
                    acc[c] = fmaf(f[c + j], w, acc[c]);
            }
        }
        // stage out into consumed slice-0 region [0,625) (< 961+pre, no clash
        // with in-flight chunks 4-7 at [1024,2048))
        const int fb = oy * OW + c0;
        #pragma unroll
        for (int c = 0; c < 12; ++c) xsw[fb + c] = acc[c] * 0.001f;
        if (!h) xsw[fb + 12] = acc[12] * 0.001f;
    }

    // ================= all x resident; copy A drains under phase B ==============
    asm volatile("s_waitcnt vmcnt(0)" ::: "memory");
    __builtin_amdgcn_sched_barrier(0);
    #pragma unroll
    for (int k = 0; k < 9; ++k) og[k * 64 + lane] = xsw[k * 64 + lane];
    if (lane < SLICE_O - 576) og[576 + lane] = xsw[576 + lane];   // 49 tail

    // ================= phase B: slice 1 =========================================
    if (act) {
        float acc[13] = {};
        const float* __restrict__ xrow = xsw + pre + SLICE_X;
        const float* __restrict__ zs = zw + KH * KW;
        #pragma unroll
        for (int i = 0; i < KH; ++i) {
            const float* __restrict__ p = xrow + (oy + i) * XW + c0;
            float f[19];
            #pragma unroll
            for (int c = 0; c < 19; ++c) f[c] = p[c];
            #pragma unroll
            for (int j = 0; j < KW; ++j) {
                const float w = zs[i * KW + j];
                #pragma unroll
                for (int c = 0; c < 13; ++c)
                    acc[c] = fmaf(f[c + j], w, acc[c]);
            }
        }
        const int fb = SLICE_O + oy * OW + c0;            // [625,1250): slice-1 x consumed
        #pragma unroll
        for (int c = 0; c < 12; ++c) xsw[fb + c] = acc[c] * 0.001f;
        if (!h) xsw[fb + 12] = acc[12] * 0.001f;
    }
    #pragma unroll
    for (int k = 0; k < 9; ++k)
        og[SLICE_O + k * 64 + lane] = xsw[SLICE_O + k * 64 + lane];
    if (lane < SLICE_O - 576)
        og[SLICE_O + 576 + lane] = xsw[SLICE_O + 576 + lane];
}

extern "C" void kernel_launch(void* const* d_in, const int* in_sizes, int n_in,
                              void* d_out, int out_size, void* d_ws, size_t ws_size,
                              hipStream_t stream) {
    const float* z = (const float*)d_in[0];   // (64,256,7,7)
    const float* x = (const float*)d_in[1];   // (64,256,31,31)
    float* out = (float*)d_out;               // (64,256,25,25)
    const int nblk = NSLICE / SPB;            // 4096, exact
    xcorr_dw_kernel<<<dim3(nblk), dim3(THREADS), 0, stream>>>(z, x, out);
}